// Round 7
// baseline (2156.982 us; speedup 1.0000x reference)
//
#include <hip/hip_runtime.h>

// Seq2Seq LSTM (enc 512 + dec 256 steps), H=50, B=2048, in/out dim 1.
//
// Round-19: MB=2 retile -- 2 LSTM cells per lane (was 4). Evidence: in-order
// wave issue (r16: +1 indep chain = +436cy = its issue count exactly) makes
// step time = issue + stalls; r18's issue is dominated by per-lane
// activation work (4 cells: 16 sigm + 4 tanh ~ 530cy of ~700). With MB=2,
// A-rows m = b*8 + dup*2 + s carry 4x dup, so kg-pairs hold duplicate cell
// data and cells split across the pair: lane (c,kg) owns ugroups
// {2(kg&1), 2(kg&1)+1} only -> 8 sums, 8 sigm, 2 tanh, half the pack.
// MFMA count unchanged (32, wave-wide). Split combine = acc[0]+acc[1]
// in-lane. Grid 1024 blocks x 1 wave = 1 wave/SIMD chip-wide.
//
// Position permutation: pos p <-> unit us = 32*(d>>4) + (d&15) + 16*e,
// d=p>>1, e=p&1. Producer lane (c,kg)'s two units u0=32*(kg&1)+c, u1=u0+16
// land at adjacent positions p0=32*(kg&1)+2c, p0+1 -> one b32 write per
// split. Reader a0/a1 = contiguous b128 at positions kg*8 / 32+kg*8.
// Weight k-order permuted at load to match (exact).
//
// Math identical to r17/r18 (absmax 4.88e-4): fp16 weights (rel 2^-11),
// fp16-split h (h = h0 + h1), L2E folded into weights/bias (g-gate doubled
// -> tanh via sigm). Stage-major activation (r18).
//
// Fragment maps (verified r10-r18): A[m=lane&15][k=(lane>>4)*8+j],
// B[n=lane&15][k=kt*32+(lane>>4)*8+j], D col=lane&15, row=4*(lane>>4)+reg.

#define HID 50
#define SEQ 512
#define TGT 256
#define MB  2
#define NT  16                   // 4 gates x 4 unit-groups
#define L2E 1.44269504088896341f

typedef __attribute__((ext_vector_type(8))) _Float16 half8;
typedef __attribute__((ext_vector_type(2))) _Float16 half2v;
typedef __attribute__((ext_vector_type(4))) float f32x4;

#define MFMA16(A, B, C) __builtin_amdgcn_mfma_f32_16x16x32_f16((A), (B), (C), 0, 0, 0)

// One step, stage-major, 2 cells/lane. XV = x scalar for batch kgb (enters
// at the sum stage, post-MFMA -> decoder feedback off the gemv path).
// Reads h from hs[IB], writes h' to hs[OB] (2 x ds_write_b32).
#define GSTEP(XV, IB, OB)                                                   \
    {                                                                       \
        const _Float16* hp_ = &hs[IB][sA][ab][0];                           \
        half8 a0 = *(const half8*)(hp_ + kg * 8);        /* pos 0..31  */   \
        half8 a1 = *(const half8*)(hp_ + 32 + kg * 8);   /* pos 32..63 */   \
        f32x4 acc[NT];                                                      \
        _Pragma("unroll")                                                   \
        for (int j = 0; j < NT; ++j) {                                      \
            f32x4 z = {0.0f, 0.0f, 0.0f, 0.0f};                             \
            z = MFMA16(a0, Bw[j][0], z);                                    \
            z = MFMA16(a1, Bw[j][1], z);                                    \
            acc[j] = z;                                                     \
        }                                                                   \
        float xv_ = (XV);                                                   \
        float sm[8], E_[8], R_[8];                                          \
        _Pragma("unroll")                                                   \
        for (int g = 0; g < 4; ++g)                                         \
            _Pragma("unroll")                                               \
            for (int l = 0; l < 2; ++l) {                                   \
                int j = g * 4 + ugp2 + l, i = g * 2 + l;                    \
                sm[i] = acc[j][0] + acc[j][1] + fmaf(wx[i], xv_, bb[i]);    \
            }                                                               \
        _Pragma("unroll")                                                   \
        for (int i = 0; i < 8; ++i)                                         \
            E_[i] = __builtin_amdgcn_exp2f(-sm[i]);                         \
        _Pragma("unroll")                                                   \
        for (int i = 0; i < 8; ++i)                                         \
            R_[i] = __builtin_amdgcn_rcpf(1.0f + E_[i]);                    \
        float e2_[2], r2_[2];                                               \
        _Pragma("unroll")                                                   \
        for (int l = 0; l < 2; ++l) {   /* i=R[0+l] f=R[2+l] g=R[4+l] */    \
            float vg = fmaf(2.0f, R_[4 + l], -1.0f);                        \
            cc[l] = fmaf(R_[2 + l], cc[l], R_[l] * vg);                     \
            e2_[l] = __builtin_amdgcn_exp2f(-2.0f * L2E * cc[l]);           \
        }                                                                   \
        _Pragma("unroll")                                                   \
        for (int l = 0; l < 2; ++l)                                         \
            r2_[l] = __builtin_amdgcn_rcpf(1.0f + e2_[l]);                  \
        half2v w0_, w1_;                                                    \
        _Pragma("unroll")                                                   \
        for (int l = 0; l < 2; ++l) {   /* o = R[6+l] */                    \
            hv[l] = R_[6 + l] * fmaf(2.0f, r2_[l], -1.0f);                  \
            _Float16 q0 = (_Float16)hv[l];                                  \
            w0_[l] = q0;                                                    \
            w1_[l] = (_Float16)(hv[l] - (float)q0);                         \
        }                                                                   \
        *(half2v*)&hs[OB][0][kgb][p0] = w0_;        /* split0, b32 */       \
        *(half2v*)&hs[OB][1][kgb][p0] = w1_;        /* split1, b32 */       \
    }

// Decoder step: GSTEP + in-lane fc dot + 32-lane butterfly; y -> ys, xc.
#define DSTEP(T, IB, OB)                                                    \
    {                                                                       \
        GSTEP(xc, IB, OB)                                                   \
        float p = fmaf(fcw0, hv[0], fcw1 * hv[1]);                          \
        p += __shfl_xor(p, 1, 64);                                          \
        p += __shfl_xor(p, 2, 64);                                          \
        p += __shfl_xor(p, 4, 64);                                          \
        p += __shfl_xor(p, 8, 64);                                          \
        p += __shfl_xor(p, 16, 64);                                         \
        float y = p + fb;                                                   \
        if ((lane & 31) == 0) ys[kgb][T] = y;                               \
        xc = y;                                                             \
    }

extern "C" __global__ void __launch_bounds__(64, 1)
seq2seq_kernel(const float* __restrict__ src,
               const float* __restrict__ eWih, const float* __restrict__ eWhh,
               const float* __restrict__ eBih, const float* __restrict__ eBhh,
               const float* __restrict__ dWih, const float* __restrict__ dWhh,
               const float* __restrict__ dBih, const float* __restrict__ dBhh,
               const float* __restrict__ fcW, const float* __restrict__ fcB,
               float* __restrict__ out) {
    const int lane = threadIdx.x & 63;
    const int c    = lane & 15;          // D col / A row m
    const int kg   = lane >> 4;          // A/B k-octet; D row group
    const int kgb  = kg >> 1;            // this lane's cell batch
    const int ugp  = kg & 1;             // this lane's ugroup pair
    const int ugp2 = 2 * ugp;
    const int ab   = c >> 3;             // A-row m -> source batch
    const int sA   = c & 1;              // A-row m -> source h-split
    const int b0   = blockIdx.x * MB;
    const int p0   = 32 * ugp + 2 * c;   // h-write position (halves)

    // hs[buf][split][batch][72 pos(64 used; 144B stride for bank spread)]
    __shared__ __align__(16) _Float16 hs[2][2][MB][72];
    __shared__ __align__(16) float srcT[MB][SEQ];          // [batch][t]
    __shared__ __align__(16) float ys[MB][TGT];            // decoder outputs

    for (int i = lane; i < 2 * 2 * MB * 72 / 2; i += 64) ((int*)hs)[i] = 0;
    for (int i = lane; i < SEQ * MB; i += 64) {
        int e = i >> 9, t = i & 511;                       // coalesced in t
        srcT[e][t] = src[(size_t)(b0 + e) * SEQ + t];
    }
    // single wave: DS pipe is in-order; no barrier needed anywhere

    half8 Bw[NT][2];                     // [tile=(g*4+ug)][kt] fp16 weights
    float wx[8], bb[8];                  // [g*2+l] for MY 2 cells
    float cc[2] = {0.0f, 0.0f};
    float hv[2];

    auto loadW = [&](const float* Wih, const float* Whh,
                     const float* Bih, const float* Bhh) {
#pragma unroll
        for (int j = 0; j < NT; ++j) {
            const int g  = j >> 2, ug = j & 3;             // tile=(gate,ug)
            const int u  = ug * 16 + c;                    // output unit
            const bool uv = (u < HID);
            const float sc = (g == 2) ? 2.0f * L2E : L2E;  // tanh fold
            const int row = g * HID + (uv ? u : 0);        // PyTorch g*50+u
#pragma unroll
            for (int kt = 0; kt < 2; ++kt) {
                half8 s0;
#pragma unroll
                for (int jj = 0; jj < 8; ++jj) {
                    int p = kt * 32 + kg * 8 + jj;         // k position
                    int d = p >> 1, e = p & 1;
                    int us = 32 * (d >> 4) + (d & 15) + 16 * e;  // unit@pos
                    float wv = (uv && us < HID)
                             ? Whh[(size_t)row * HID + us] * sc : 0.0f;
                    s0[jj] = (_Float16)wv;
                }
                Bw[j][kt] = s0;
            }
        }
#pragma unroll
        for (int g = 0; g < 4; ++g)
#pragma unroll
            for (int l = 0; l < 2; ++l) {                  // my cells
                const int u = (ugp2 + l) * 16 + c;
                const bool uv = (u < HID);
                const float sc = (g == 2) ? 2.0f * L2E : L2E;
                const int row = g * HID + (uv ? u : 0);
                wx[g * 2 + l] = uv ? Wih[row] * sc : 0.0f;
                bb[g * 2 + l] = uv ? (Bih[row] + Bhh[row]) * sc : 0.0f;
            }
    };

    // ---------------- encoder: 512 steps (x2 unroll, h dbuf) -------------
    loadW(eWih, eWhh, eBih, eBhh);
    for (int t = 0; t < SEQ; t += 2) {
        float2 xp = *(const float2*)&srcT[kgb][t];
        { GSTEP(xp.x, 0, 1) }
        { GSTEP(xp.y, 1, 0) }
    }
    // h(512) in buf 0; cc persists in registers

    // ---------------- decoder: 256 steps (x2 unroll) ---------------------
    loadW(dWih, dWhh, dBih, dBhh);
    const int u0f = 32 * ugp + c;        // my cell units for fc
    const int u1f = u0f + 16;
    const float fcw0 = fcW[u0f];         // u0f <= 47 < HID always
    const float fcw1 = (u1f < HID) ? fcW[u1f] : 0.0f;
    const float fb   = fcB[0];
    float xc = 0.0f;                     // decoder_input = zeros
    for (int t = 0; t < TGT; t += 2) {
        DSTEP(t,     0, 1)
        DSTEP(t + 1, 1, 0)
    }

    // coalesced output write
    for (int i = lane; i < MB * TGT; i += 64) {
        int b = i >> 8, t = i & 255;
        out[(size_t)(b0 + b) * TGT + t] = ys[b][t];
    }
}

extern "C" void kernel_launch(void* const* d_in, const int* in_sizes, int n_in,
                              void* d_out, int out_size, void* d_ws, size_t ws_size,
                              hipStream_t stream) {
    const float* src  = (const float*)d_in[0];
    const float* eWih = (const float*)d_in[1];
    const float* eWhh = (const float*)d_in[2];
    const float* eBih = (const float*)d_in[3];
    const float* eBhh = (const float*)d_in[4];
    const float* dWih = (const float*)d_in[5];
    const float* dWhh = (const float*)d_in[6];
    const float* dBih = (const float*)d_in[7];
    const float* dBhh = (const float*)d_in[8];
    const float* fcW  = (const float*)d_in[9];
    const float* fcB  = (const float*)d_in[10];
    float* out = (float*)d_out;

    const int B = in_sizes[0] / SEQ;     // 2048
    seq2seq_kernel<<<B / MB, 64, 0, stream>>>(src, eWih, eWhh, eBih, eBhh,
                                              dWih, dWhh, dBih, dBhh,
                                              fcW, fcB, out);
}

// Round 8
// 495.023 us; speedup vs baseline: 4.3573x; 4.3573x over previous
//
#include <hip/hip_runtime.h>

// Seq2Seq LSTM (enc 512 + dec 256 steps), H=50, B=2048, in/out dim 1.
//
// Round-20: r19 (MB=2, 2 cells/lane) with the SCRATCH-SPILL FIXED.
// r19 indexed acc[g*4 + ugp2 + l] with runtime ugp2 -> rule #20: the whole
// acc[16] f32x4 array went to local memory (WRITE_SIZE 2048KB -> 2.4GB,
// dur 2157us). Fix: reduce all 16 accumulators with STATIC indices
// (sums[j] = acc[j][0] + acc[j][1]), then pick this lane's pair with a
// ternary on ugp -> v_cndmask, no memory. Everything else identical to
// r19, so this cleanly tests the MB=2 hypothesis (per-lane activation
// issue halves: 8 sigm + 2 tanh vs r18's 16 + 4).
//
// Structure: 1 wave = 1 block = 2 batches, barrier-free (r17/r18 host).
// A-rows m = b*8 + dup*2 + s (4x dup); lane (c,kg) owns cells
// (batch kg>>1, units {32*(kg&1)+c, +16}). MFMA 32/step (wave-wide).
// Split combine = acc[0]+acc[1]. Grid 1024 blocks = 1 wave/SIMD.
//
// Position permutation: pos p <-> unit us = 32*(d>>4) + (d&15) + 16*e,
// d=p>>1, e=p&1. Producer writes one b32 per split at p0=32*(kg&1)+2c.
// Weight k-order permuted at load to match (exact).
//
// Math identical to r17-r19 (absmax 4.88e-4): fp16 weights (rel 2^-11),
// fp16-split h (h = h0 + h1), L2E folded into weights/bias (g-gate
// doubled -> tanh via sigm). Stage-major activation (r18).

#define HID 50
#define SEQ 512
#define TGT 256
#define MB  2
#define NT  16                   // 4 gates x 4 unit-groups
#define L2E 1.44269504088896341f

typedef __attribute__((ext_vector_type(8))) _Float16 half8;
typedef __attribute__((ext_vector_type(2))) _Float16 half2v;
typedef __attribute__((ext_vector_type(4))) float f32x4;

#define MFMA16(A, B, C) __builtin_amdgcn_mfma_f32_16x16x32_f16((A), (B), (C), 0, 0, 0)

// One step, stage-major, 2 cells/lane, ALL register indices static.
#define GSTEP(XV, IB, OB)                                                   \
    {                                                                       \
        const _Float16* hp_ = &hs[IB][sA][ab][0];                           \
        half8 a0 = *(const half8*)(hp_ + kg * 8);        /* pos 0..31  */   \
        half8 a1 = *(const half8*)(hp_ + 32 + kg * 8);   /* pos 32..63 */   \
        f32x4 acc[NT];                                                      \
        _Pragma("unroll")                                                   \
        for (int j = 0; j < NT; ++j) {                                      \
            f32x4 z = {0.0f, 0.0f, 0.0f, 0.0f};                             \
            z = MFMA16(a0, Bw[j][0], z);                                    \
            z = MFMA16(a1, Bw[j][1], z);                                    \
            acc[j] = z;                                                     \
        }                                                                   \
        float sums[NT];                                                     \
        _Pragma("unroll")                                                   \
        for (int j = 0; j < NT; ++j)                                        \
            sums[j] = acc[j][0] + acc[j][1];      /* static idx only */     \
        float xv_ = (XV);                                                   \
        float sm[8], E_[8], R_[8];                                          \
        _Pragma("unroll")                                                   \
        for (int g = 0; g < 4; ++g)                                         \
            _Pragma("unroll")                                               \
            for (int l = 0; l < 2; ++l) {                                   \
                int i = g * 2 + l;                                          \
                float sel = ugp ? sums[g * 4 + 2 + l] : sums[g * 4 + l];    \
                sm[i] = sel + fmaf(wx[i], xv_, bb[i]);                      \
            }                                                               \
        _Pragma("unroll")                                                   \
        for (int i = 0; i < 8; ++i)                                         \
            E_[i] = __builtin_amdgcn_exp2f(-sm[i]);                         \
        _Pragma("unroll")                                                   \
        for (int i = 0; i < 8; ++i)                                         \
            R_[i] = __builtin_amdgcn_rcpf(1.0f + E_[i]);                    \
        float e2_[2], r2_[2];                                               \
        _Pragma("unroll")                                                   \
        for (int l = 0; l < 2; ++l) {   /* i=R[0+l] f=R[2+l] g=R[4+l] */    \
            float vg = fmaf(2.0f, R_[4 + l], -1.0f);                        \
            cc[l] = fmaf(R_[2 + l], cc[l], R_[l] * vg);                     \
            e2_[l] = __builtin_amdgcn_exp2f(-2.0f * L2E * cc[l]);           \
        }                                                                   \
        _Pragma("unroll")                                                   \
        for (int l = 0; l < 2; ++l)                                         \
            r2_[l] = __builtin_amdgcn_rcpf(1.0f + e2_[l]);                  \
        half2v w0_, w1_;                                                    \
        _Pragma("unroll")                                                   \
        for (int l = 0; l < 2; ++l) {   /* o = R[6+l] */                    \
            hv[l] = R_[6 + l] * fmaf(2.0f, r2_[l], -1.0f);                  \
            _Float16 q0 = (_Float16)hv[l];                                  \
            w0_[l] = q0;                                                    \
            w1_[l] = (_Float16)(hv[l] - (float)q0);                         \
        }                                                                   \
        *(half2v*)&hs[OB][0][kgb][p0] = w0_;        /* split0, b32 */       \
        *(half2v*)&hs[OB][1][kgb][p0] = w1_;        /* split1, b32 */       \
    }

// Decoder step: GSTEP + in-lane fc dot + 32-lane butterfly; y -> ys, xc.
#define DSTEP(T, IB, OB)                                                    \
    {                                                                       \
        GSTEP(xc, IB, OB)                                                   \
        float p = fmaf(fcw0, hv[0], fcw1 * hv[1]);                          \
        p += __shfl_xor(p, 1, 64);                                          \
        p += __shfl_xor(p, 2, 64);                                          \
        p += __shfl_xor(p, 4, 64);                                          \
        p += __shfl_xor(p, 8, 64);                                          \
        p += __shfl_xor(p, 16, 64);                                         \
        float y = p + fb;                                                   \
        if ((lane & 31) == 0) ys[kgb][T] = y;                               \
        xc = y;                                                             \
    }

extern "C" __global__ void __launch_bounds__(64, 1)
seq2seq_kernel(const float* __restrict__ src,
               const float* __restrict__ eWih, const float* __restrict__ eWhh,
               const float* __restrict__ eBih, const float* __restrict__ eBhh,
               const float* __restrict__ dWih, const float* __restrict__ dWhh,
               const float* __restrict__ dBih, const float* __restrict__ dBhh,
               const float* __restrict__ fcW, const float* __restrict__ fcB,
               float* __restrict__ out) {
    const int lane = threadIdx.x & 63;
    const int c    = lane & 15;          // D col / A row m
    const int kg   = lane >> 4;          // A/B k-octet; D row group
    const int kgb  = kg >> 1;            // this lane's cell batch
    const int ugp  = kg & 1;             // this lane's ugroup pair
    const int ab   = c >> 3;             // A-row m -> source batch
    const int sA   = c & 1;              // A-row m -> source h-split
    const int b0   = blockIdx.x * MB;
    const int p0   = 32 * ugp + 2 * c;   // h-write position (halves)

    // hs[buf][split][batch][72 pos(64 used; 144B stride for bank spread)]
    __shared__ __align__(16) _Float16 hs[2][2][MB][72];
    __shared__ __align__(16) float srcT[MB][SEQ];          // [batch][t]
    __shared__ __align__(16) float ys[MB][TGT];            // decoder outputs

    for (int i = lane; i < 2 * 2 * MB * 72 / 2; i += 64) ((int*)hs)[i] = 0;
    for (int i = lane; i < SEQ * MB; i += 64) {
        int e = i >> 9, t = i & 511;                       // coalesced in t
        srcT[e][t] = src[(size_t)(b0 + e) * SEQ + t];
    }
    // single wave: DS pipe is in-order; no barrier needed anywhere

    half8 Bw[NT][2];                     // [tile=(g*4+ug)][kt] fp16 weights
    float wx[8], bb[8];                  // [g*2+l] for MY 2 cells
    float cc[2] = {0.0f, 0.0f};
    float hv[2];

    auto loadW = [&](const float* Wih, const float* Whh,
                     const float* Bih, const float* Bhh) {
#pragma unroll
        for (int j = 0; j < NT; ++j) {
            const int g  = j >> 2, ug = j & 3;             // tile=(gate,ug)
            const int u  = ug * 16 + c;                    // output unit
            const bool uv = (u < HID);
            const float sc = (g == 2) ? 2.0f * L2E : L2E;  // tanh fold
            const int row = g * HID + (uv ? u : 0);        // PyTorch g*50+u
#pragma unroll
            for (int kt = 0; kt < 2; ++kt) {
                half8 s0;
#pragma unroll
                for (int jj = 0; jj < 8; ++jj) {
                    int p = kt * 32 + kg * 8 + jj;         // k position
                    int d = p >> 1, e = p & 1;
                    int us = 32 * (d >> 4) + (d & 15) + 16 * e;  // unit@pos
                    float wv = (uv && us < HID)
                             ? Whh[(size_t)row * HID + us] * sc : 0.0f;
                    s0[jj] = (_Float16)wv;
                }
                Bw[j][kt] = s0;
            }
        }
#pragma unroll
        for (int g = 0; g < 4; ++g)
#pragma unroll
            for (int l = 0; l < 2; ++l) {                  // my cells
                const int u = (2 * ugp + l) * 16 + c;
                const bool uv = (u < HID);
                const float sc = (g == 2) ? 2.0f * L2E : L2E;
                const int row = g * HID + (uv ? u : 0);
                wx[g * 2 + l] = uv ? Wih[row] * sc : 0.0f;
                bb[g * 2 + l] = uv ? (Bih[row] + Bhh[row]) * sc : 0.0f;
            }
    };

    // ---------------- encoder: 512 steps (x2 unroll, h dbuf) -------------
    loadW(eWih, eWhh, eBih, eBhh);
    for (int t = 0; t < SEQ; t += 2) {
        float2 xp = *(const float2*)&srcT[kgb][t];
        { GSTEP(xp.x, 0, 1) }
        { GSTEP(xp.y, 1, 0) }
    }
    // h(512) in buf 0; cc persists in registers

    // ---------------- decoder: 256 steps (x2 unroll) ---------------------
    loadW(dWih, dWhh, dBih, dBhh);
    const int u0f = 32 * ugp + c;        // my cell units for fc
    const int u1f = u0f + 16;
    const float fcw0 = fcW[u0f];         // u0f <= 47 < HID always
    const float fcw1 = (u1f < HID) ? fcW[u1f] : 0.0f;
    const float fb   = fcB[0];
    float xc = 0.0f;                     // decoder_input = zeros
    for (int t = 0; t < TGT; t += 2) {
        DSTEP(t,     0, 1)
        DSTEP(t + 1, 1, 0)
    }

    // coalesced output write
    for (int i = lane; i < MB * TGT; i += 64) {
        int b = i >> 8, t = i & 255;
        out[(size_t)(b0 + b) * TGT + t] = ys[b][t];
    }
}

extern "C" void kernel_launch(void* const* d_in, const int* in_sizes, int n_in,
                              void* d_out, int out_size, void* d_ws, size_t ws_size,
                              hipStream_t stream) {
    const float* src  = (const float*)d_in[0];
    const float* eWih = (const float*)d_in[1];
    const float* eWhh = (const float*)d_in[2];
    const float* eBih = (const float*)d_in[3];
    const float* eBhh = (const float*)d_in[4];
    const float* dWih = (const float*)d_in[5];
    const float* dWhh = (const float*)d_in[6];
    const float* dBih = (const float*)d_in[7];
    const float* dBhh = (const float*)d_in[8];
    const float* fcW  = (const float*)d_in[9];
    const float* fcB  = (const float*)d_in[10];
    float* out = (float*)d_out;

    const int B = in_sizes[0] / SEQ;     // 2048
    seq2seq_kernel<<<B / MB, 64, 0, stream>>>(src, eWih, eWhh, eBih, eBhh,
                                              dWih, dWhh, dBih, dBhh,
                                              fcW, fcB, out);
}